// Round 2
// baseline (169.885 us; speedup 1.0000x reference)
//
#include <hip/hip_runtime.h>
#include <hip/hip_bf16.h>
#include <stdint.h>

// ColBERT MaxSim on MI355X (gfx950)
// prep (W^T->bf16 swizzled + mask) | proj (MFMA bf16, fused f32->bf16 LDS
// staging, L2-normalize, plain bf16 reps) | score (MFMA bf16, Q & D frags
// straight from L2-resident global reps, rowmax + masked sum, atomicAdd).
//
// Round-1 change (no HW data yet; design-audit driven): score's LDS D-tile
// had ZERO cross-wave reuse (each wave read a disjoint 64-row slice) ->
// staging was pure overhead. Dropped it; reps stored UNSWIZZLED; score has
// no barriers in the compute path. WT keeps its chunk-XOR swizzle (proj
// reads it through LDS with row-varying-lane pattern -> would 16-way
// conflict otherwise).

#define BQ 32
#define LQ 256
#define V  768
#define DIM 128
#define NQ (BQ * LQ)       // 8192 query tokens
#define ND (BQ * LQ)       // 8192 doc tokens

typedef short bf16x8 __attribute__((ext_vector_type(8)));
typedef float f32x4 __attribute__((ext_vector_type(4)));
typedef float fvec4 __attribute__((ext_vector_type(4)));
typedef unsigned short us4 __attribute__((ext_vector_type(4)));

__device__ inline unsigned short f2bf(float f) {
  __hip_bfloat16 h = __float2bfloat16(f);
  unsigned short u;
  __builtin_memcpy(&u, &h, 2);
  return u;
}

__device__ inline void gload_lds16(const void* g, void* lds) {
  __builtin_amdgcn_global_load_lds(
      (const __attribute__((address_space(1))) void*)g,
      (__attribute__((address_space(3))) void*)lds, 16, 0, 0);
}

// ---------------------------------------------------------------------------
// prep: blocks 0..383 -> W [768][128] f32 -> WT bf16 [n][k] (128 x 768),
// per-row chunk swizzle (16B chunk c at c ^ (n&7) within each 128B group,
// row stride 1536 B). Blocks 384..415 -> query mask: zero [CLS] + [SEP].
__global__ void prep_kernel(const float* __restrict__ W,
                            unsigned short* __restrict__ WT,
                            const int* __restrict__ mask,
                            float* __restrict__ wmask) {
  if (blockIdx.x < 384) {
    int idx = blockIdx.x * 256 + threadIdx.x;  // idx = k*128 + n
    int n = idx & 127;
    int k = idx >> 7;
    float v = W[idx];
    int kg = k >> 6;
    int kc = k & 63;
    int wb = ((((kc >> 3) ^ (n & 7)) << 4) | ((kc & 7) << 1));
    *(unsigned short*)((char*)WT + (size_t)n * 1536 + kg * 128 + wb) = f2bf(v);
  } else {
    int b = blockIdx.x - 384, t = threadIdx.x;
    int m = mask[b * 256 + t];
    int s = m;
    #pragma unroll
    for (int off = 1; off < 64; off <<= 1) s += __shfl_xor(s, off, 64);
    __shared__ int ws[4];
    int w = t >> 6, l = t & 63;
    if (l == 0) ws[w] = s;
    __syncthreads();
    int total = ws[0] + ws[1] + ws[2] + ws[3];
    int sep = total - 1;
    float out = (t == 0 || t == sep) ? 0.0f : (float)m;
    wmask[b * 256 + t] = out;
  }
}

// ---------------------------------------------------------------------------
// proj: rows of [qry;doc] hidden (f32, K=768) @ W + b, L2-normalize over 128,
// store PLAIN row-major bf16 reps [row][128].
// Block: 32 rows x 128 cols, 4 waves, wave-tile 32x32. Grid: 512 blocks.
__launch_bounds__(256, 2)
__global__ void proj_kernel(const float* __restrict__ qh, const float* __restrict__ dh,
                            const unsigned short* __restrict__ WT,
                            const float* __restrict__ bias,
                            unsigned short* __restrict__ qrep,
                            unsigned short* __restrict__ drep) {
  __shared__ __align__(16) unsigned short Atile[32 * 64];   // [32][128B] swizzled, 4 KB
  __shared__ __align__(16) unsigned short Btile[128 * 64];  // [128][128B] swizzled, 16 KB
  __shared__ float sq[4][32];

  const int t = threadIdx.x;
  const int w = t >> 6;
  const int l = t & 63;
  const int lm = l & 15, lg = l >> 4;
  const int rowblk = blockIdx.x * 32;

  f32x4 acc[2][2];
  #pragma unroll
  for (int r = 0; r < 2; r++)
    #pragma unroll
    for (int c = 0; c < 2; c++)
      acc[r][c] = f32x4{0.f, 0.f, 0.f, 0.f};

  float bias_c[2];
  #pragma unroll
  for (int c = 0; c < 2; c++) bias_c[c] = bias[w * 32 + c * 16 + lm];

  for (int kk = 0; kk < 12; kk++) {
    const int k0 = kk * 64;
    // stage A: 32 rows x 16 float4 chunks; f32 -> bf16, swizzled ds_write
    #pragma unroll
    for (int p = 0; p < 2; p++) {
      int id = p * 256 + t;
      int row = id >> 4, c4 = id & 15;
      int row_g = rowblk + row;
      const float* src = (row_g < NQ) ? (qh + (size_t)row_g * V)
                                      : (dh + (size_t)(row_g - NQ) * V);
      fvec4 v = *(const fvec4*)(src + k0 + c4 * 4);
      us4 b4;
      #pragma unroll
      for (int j = 0; j < 4; j++) b4[j] = f2bf(v[j]);
      int wb = ((((c4 >> 1) ^ (row & 7)) << 4) | ((c4 & 1) << 3));
      *(us4*)((char*)Atile + row * 128 + wb) = b4;
    }
    // stage B: WT slice (pre-swizzled in global) via global_load_lds
    #pragma unroll
    for (int i = 0; i < 4; i++) {
      int off = i * 4096 + t * 16;
      int n = off >> 7;
      int inrow = off & 127;
      const void* src = (const char*)WT + (size_t)n * 1536 + kk * 128 + inrow;
      gload_lds16(src, (char*)Btile + i * 4096 + w * 1024);
    }
    __syncthreads();
    #pragma unroll
    for (int ks = 0; ks < 2; ks++) {
      bf16x8 af[2], bfr[2];
      #pragma unroll
      for (int r = 0; r < 2; r++) {
        int row = r * 16 + lm;
        int ch = (ks * 4 + lg) ^ (row & 7);
        af[r] = *(const bf16x8*)((char*)Atile + row * 128 + ch * 16);
      }
      #pragma unroll
      for (int c = 0; c < 2; c++) {
        int n = w * 32 + c * 16 + lm;
        int ch = (ks * 4 + lg) ^ (n & 7);
        bfr[c] = *(const bf16x8*)((char*)Btile + n * 128 + ch * 16);
      }
      #pragma unroll
      for (int r = 0; r < 2; r++)
        #pragma unroll
        for (int c = 0; c < 2; c++)
          acc[r][c] = __builtin_amdgcn_mfma_f32_16x16x32_bf16(af[r], bfr[c], acc[r][c], 0, 0, 0);
    }
    __syncthreads();
  }

  // epilogue: bias, sum-of-squares (lane-group shuffle -> LDS -> total),
  // normalize, plain row-major store
  float vout[2][2][4];
  float ss[2][4];
  #pragma unroll
  for (int r = 0; r < 2; r++) {
    #pragma unroll
    for (int j = 0; j < 4; j++) {
      float s = 0.f;
      #pragma unroll
      for (int c = 0; c < 2; c++) {
        float v = acc[r][c][j] + bias_c[c];
        vout[r][c][j] = v;
        s += v * v;
      }
      #pragma unroll
      for (int m = 1; m < 16; m <<= 1) s += __shfl_xor(s, m, 64);
      ss[r][j] = s;
    }
  }
  if (lm == 0) {
    #pragma unroll
    for (int r = 0; r < 2; r++)
      #pragma unroll
      for (int j = 0; j < 4; j++)
        sq[w][r * 16 + lg * 4 + j] = ss[r][j];
  }
  __syncthreads();
  #pragma unroll
  for (int r = 0; r < 2; r++) {
    #pragma unroll
    for (int j = 0; j < 4; j++) {
      int rowl = r * 16 + lg * 4 + j;
      float tot = sq[0][rowl] + sq[1][rowl] + sq[2][rowl] + sq[3][rowl];
      float inv = 1.0f / fmaxf(sqrtf(tot), 1e-12f);
      int row_g = rowblk + rowl;
      unsigned short* rep = (row_g < NQ) ? qrep : drep;
      int rl = (row_g < NQ) ? row_g : row_g - NQ;
      #pragma unroll
      for (int c = 0; c < 2; c++) {
        int col = w * 32 + c * 16 + lm;
        rep[(size_t)rl * DIM + col] = f2bf(vout[r][c][j] * inv);
      }
    }
  }
}

// ---------------------------------------------------------------------------
// score: block = 64 q-rows x one full doc batch (256 d-tokens), 4 waves,
// wave-tile 64q x 64d (r=4, c=4). Q and D fragments read DIRECTLY from
// L2-resident global reps (no LDS staging -- no cross-wave reuse existed).
// Epilogue: rowwise max over 256 d-tokens, masked sum, one atomicAdd.
__launch_bounds__(256, 2)
__global__ void score_kernel(const unsigned short* __restrict__ qrep,
                             const unsigned short* __restrict__ drep,
                             const float* __restrict__ wmask,
                             float* __restrict__ out) {
  __shared__ float maxbuf[4][64];
  __shared__ float partial[4];

  const int t = threadIdx.x;
  const int w = t >> 6, l = t & 63;
  const int lm = l & 15, lg = l >> 4;
  const int db = blockIdx.x;    // doc batch 0..31
  const int qt = blockIdx.y;    // q tile 0..127
  const int qrow0 = qt * 64;

  // Q fragments into registers (plain layout: row*128 + ks*32 + lg*8)
  bf16x8 qf[4][4];
  #pragma unroll
  for (int r = 0; r < 4; r++) {
    const unsigned short* qbase = qrep + (size_t)(qrow0 + r * 16 + lm) * DIM;
    #pragma unroll
    for (int ks = 0; ks < 4; ks++)
      qf[r][ks] = *(const bf16x8*)(qbase + ks * 32 + lg * 8);
  }

  f32x4 acc[4][4];
  #pragma unroll
  for (int r = 0; r < 4; r++)
    #pragma unroll
    for (int c = 0; c < 4; c++)
      acc[r][c] = f32x4{0.f, 0.f, 0.f, 0.f};

  const unsigned short* dbase = drep + (size_t)db * (256 * DIM);
  #pragma unroll
  for (int c = 0; c < 4; c++) {
    const unsigned short* dptr = dbase + (size_t)(w * 64 + c * 16 + lm) * DIM;
    #pragma unroll
    for (int ks = 0; ks < 4; ks++) {
      bf16x8 bfr = *(const bf16x8*)(dptr + ks * 32 + lg * 8);
      #pragma unroll
      for (int r = 0; r < 4; r++)
        acc[r][c] = __builtin_amdgcn_mfma_f32_16x16x32_bf16(qf[r][ks], bfr, acc[r][c], 0, 0, 0);
    }
  }

  // rowwise max over this wave's 64 d-cols (C layout: col=l&15, row=lg*4+j)
  #pragma unroll
  for (int r = 0; r < 4; r++) {
    #pragma unroll
    for (int j = 0; j < 4; j++) {
      float m = acc[r][0][j];
      #pragma unroll
      for (int c = 1; c < 4; c++) m = fmaxf(m, acc[r][c][j]);
      #pragma unroll
      for (int msk = 1; msk < 16; msk <<= 1) m = fmaxf(m, __shfl_xor(m, msk, 64));
      if (lm == 0) maxbuf[w][r * 16 + lg * 4 + j] = m;
    }
  }
  __syncthreads();

  float contrib = 0.0f;
  if (t < 64) {
    float m = fmaxf(fmaxf(maxbuf[0][t], maxbuf[1][t]),
                    fmaxf(maxbuf[2][t], maxbuf[3][t]));
    contrib = m * wmask[qrow0 + t];
  }
  #pragma unroll
  for (int off = 1; off < 64; off <<= 1) contrib += __shfl_xor(contrib, off, 64);
  if (l == 0) partial[w] = contrib;
  __syncthreads();
  if (t == 0) {
    float s = partial[0] + partial[1] + partial[2] + partial[3];
    int qb = qrow0 >> 8;
    atomicAdd(&out[qb * 32 + db], s);
  }
}

// ---------------------------------------------------------------------------
extern "C" void kernel_launch(void* const* d_in, const int* in_sizes, int n_in,
                              void* d_out, int out_size, void* d_ws, size_t ws_size,
                              hipStream_t stream) {
  const float* qh  = (const float*)d_in[0];
  const float* dh  = (const float*)d_in[1];
  const float* W   = (const float*)d_in[2];
  const float* b   = (const float*)d_in[3];
  const int* mask  = (const int*)d_in[4];
  float* out = (float*)d_out;

  char* ws = (char*)d_ws;
  unsigned short* qrep = (unsigned short*)(ws);                         // 2 MB
  unsigned short* drep = (unsigned short*)(ws + (1 << 21));             // 2 MB
  unsigned short* WT   = (unsigned short*)(ws + (1 << 22));             // 192 KB
  float* wmaskp        = (float*)(ws + (1 << 22) + (192 << 10));        // 32 KB

  hipMemsetAsync(d_out, 0, (size_t)out_size * sizeof(float), stream);
  prep_kernel<<<416, 256, 0, stream>>>(W, WT, mask, wmaskp);
  proj_kernel<<<512, 256, 0, stream>>>(qh, dh, WT, b, qrep, drep);
  score_kernel<<<dim3(32, 128), 256, 0, stream>>>(qrep, drep, wmaskp, out);
}

// Round 5
// 118.501 us; speedup vs baseline: 1.4336x; 1.4336x over previous
//
#include <hip/hip_runtime.h>
#include <hip/hip_bf16.h>
#include <stdint.h>
#include <math.h>

// ColBERT MaxSim on MI355X (gfx950)
// prep (W^T->bf16 swizzled + mask) | proj (16x16x32 MFMA, dbuf LDS, T14
// async A-prefetch, L2-normalize, 16-slot-swizzled bf16 reps) | score
// (32x32x16 MFMA, D=A/Q=B orientation so doc-max is in-register, Q-tile
// staged once + Q-frags hoisted, D chunks double-buffered via
// global_load_lds, maxAll overlay on dead Q-tile, direct stores, no atomics).

#define BQ 32
#define LQ 256
#define V  768
#define DIM 128
#define NQ (BQ * LQ)       // 8192 query tokens
#define ND (BQ * LQ)       // 8192 doc tokens

typedef short bf16x8 __attribute__((ext_vector_type(8)));
typedef float f32x4  __attribute__((ext_vector_type(4)));
typedef float f32x16 __attribute__((ext_vector_type(16)));
typedef float fvec4  __attribute__((ext_vector_type(4)));
typedef unsigned short us4 __attribute__((ext_vector_type(4)));

__device__ inline unsigned short f2bf(float f) {
  __hip_bfloat16 h = __float2bfloat16(f);
  unsigned short u;
  __builtin_memcpy(&u, &h, 2);
  return u;
}

__device__ inline void gload_lds16(const void* g, void* lds) {
  __builtin_amdgcn_global_load_lds(
      (const __attribute__((address_space(1))) void*)g,
      (__attribute__((address_space(3))) void*)lds, 16, 0, 0);
}

// ---------------------------------------------------------------------------
// prep: blocks 0..383 -> W [768][128] f32 -> WT bf16 [n][k] (128 x 768),
// 8-slot chunk swizzle key (n&7), row stride 1536 B (consumed by proj's LDS
// path). Blocks 384..415 -> query mask: zero [CLS] + [SEP].
__global__ void prep_kernel(const float* __restrict__ W,
                            unsigned short* __restrict__ WT,
                            const int* __restrict__ mask,
                            float* __restrict__ wmask) {
  if (blockIdx.x < 384) {
    int idx = blockIdx.x * 256 + threadIdx.x;  // idx = k*128 + n
    int n = idx & 127;
    int k = idx >> 7;
    float v = W[idx];
    int kg = k >> 6;
    int kc = k & 63;
    int wb = ((((kc >> 3) ^ (n & 7)) << 4) | ((kc & 7) << 1));
    *(unsigned short*)((char*)WT + (size_t)n * 1536 + kg * 128 + wb) = f2bf(v);
  } else {
    int b = blockIdx.x - 384, t = threadIdx.x;
    int m = mask[b * 256 + t];
    int s = m;
    #pragma unroll
    for (int off = 1; off < 64; off <<= 1) s += __shfl_xor(s, off, 64);
    __shared__ int ws[4];
    int w = t >> 6, l = t & 63;
    if (l == 0) ws[w] = s;
    __syncthreads();
    int total = ws[0] + ws[1] + ws[2] + ws[3];
    int sep = total - 1;
    float out = (t == 0 || t == sep) ? 0.0f : (float)m;
    wmask[b * 256 + t] = out;
  }
}

// ---------------------------------------------------------------------------
// proj: rows of [qry;doc] hidden (f32, K=768) @ W + b, L2-normalize, store
// bf16 reps with 16-slot chunk swizzle (key row&15) for score's LDS path.
// Block: 32 rows x 128 cols, 4 waves, wave-tile 32x32. Double-buffered
// A (reg-staged, T14 split) and B (global_load_lds). One barrier per K-step.
__launch_bounds__(256, 2)
__global__ void proj_kernel(const float* __restrict__ qh, const float* __restrict__ dh,
                            const unsigned short* __restrict__ WT,
                            const float* __restrict__ bias,
                            unsigned short* __restrict__ qrep,
                            unsigned short* __restrict__ drep) {
  __shared__ __align__(16) unsigned short At[2][32 * 64];   // 2 x 4 KB swizzled
  __shared__ __align__(16) unsigned short Bt[2][128 * 64];  // 2 x 16 KB swizzled
  __shared__ float sq[4][32];

  const int t = threadIdx.x;
  const int w = t >> 6;
  const int l = t & 63;
  const int lm = l & 15, lg = l >> 4;
  const int rowblk = blockIdx.x * 32;

  // per-thread A-load assignment: 2 float4 chunks (32 rows x 16 chunks)
  int arow[2], ac4[2];
  const float* asrc[2];
  #pragma unroll
  for (int p = 0; p < 2; p++) {
    int id = p * 256 + t;
    arow[p] = id >> 4;
    ac4[p] = id & 15;
    int row_g = rowblk + arow[p];
    asrc[p] = (row_g < NQ) ? (qh + (size_t)row_g * V)
                           : (dh + (size_t)(row_g - NQ) * V);
  }

  f32x4 acc[2][2];
  #pragma unroll
  for (int r = 0; r < 2; r++)
    #pragma unroll
    for (int c = 0; c < 2; c++)
      acc[r][c] = f32x4{0.f, 0.f, 0.f, 0.f};

  float bias_c[2];
  #pragma unroll
  for (int c = 0; c < 2; c++) bias_c[c] = bias[w * 32 + c * 16 + lm];

  fvec4 apref[2];
  // ---- prologue (kk = 0) ----
  #pragma unroll
  for (int p = 0; p < 2; p++) apref[p] = *(const fvec4*)(asrc[p] + ac4[p] * 4);
  #pragma unroll
  for (int i = 0; i < 4; i++) {
    int off = i * 4096 + t * 16;
    int n = off >> 7, inrow = off & 127;
    gload_lds16((const char*)WT + (size_t)n * 1536 + inrow,
                (char*)Bt[0] + i * 4096 + w * 1024);
  }
  #pragma unroll
  for (int p = 0; p < 2; p++) {
    us4 b4;
    #pragma unroll
    for (int j = 0; j < 4; j++) b4[j] = f2bf(apref[p][j]);
    int wb = ((((ac4[p] >> 1) ^ (arow[p] & 7)) << 4) | ((ac4[p] & 1) << 3));
    *(us4*)((char*)At[0] + arow[p] * 128 + wb) = b4;
  }
  __syncthreads();

  // ---- main loop: 12 K-steps of 64 ----
  for (int kk = 0; kk < 12; kk++) {
    const int cur = kk & 1;
    if (kk < 11) {
      // T14: issue next A loads early; DMA next B slice into other buffer
      #pragma unroll
      for (int p = 0; p < 2; p++)
        apref[p] = *(const fvec4*)(asrc[p] + (kk + 1) * 64 + ac4[p] * 4);
      #pragma unroll
      for (int i = 0; i < 4; i++) {
        int off = i * 4096 + t * 16;
        int n = off >> 7, inrow = off & 127;
        gload_lds16((const char*)WT + (size_t)n * 1536 + (kk + 1) * 128 + inrow,
                    (char*)Bt[cur ^ 1] + i * 4096 + w * 1024);
      }
    }
    // compute current buffers
    #pragma unroll
    for (int ks = 0; ks < 2; ks++) {
      bf16x8 af[2], bfr[2];
      #pragma unroll
      for (int r = 0; r < 2; r++) {
        int row = r * 16 + lm;
        int ch = (ks * 4 + lg) ^ (row & 7);
        af[r] = *(const bf16x8*)((char*)At[cur] + row * 128 + ch * 16);
      }
      #pragma unroll
      for (int c = 0; c < 2; c++) {
        int n = w * 32 + c * 16 + lm;
        int ch = (ks * 4 + lg) ^ (n & 7);
        bfr[c] = *(const bf16x8*)((char*)Bt[cur] + n * 128 + ch * 16);
      }
      #pragma unroll
      for (int r = 0; r < 2; r++)
        #pragma unroll
        for (int c = 0; c < 2; c++)
          acc[r][c] = __builtin_amdgcn_mfma_f32_16x16x32_bf16(af[r], bfr[c], acc[r][c], 0, 0, 0);
    }
    if (kk < 11) {
      // late half of T14 split: convert + ds_write into next buffer
      #pragma unroll
      for (int p = 0; p < 2; p++) {
        us4 b4;
        #pragma unroll
        for (int j = 0; j < 4; j++) b4[j] = f2bf(apref[p][j]);
        int wb = ((((ac4[p] >> 1) ^ (arow[p] & 7)) << 4) | ((ac4[p] & 1) << 3));
        *(us4*)((char*)At[cur ^ 1] + arow[p] * 128 + wb) = b4;
      }
    }
    __syncthreads();
  }

  // ---- epilogue: bias, sum-of-squares, normalize, swizzled store ----
  float vout[2][2][4];
  float ss[2][4];
  #pragma unroll
  for (int r = 0; r < 2; r++) {
    #pragma unroll
    for (int j = 0; j < 4; j++) {
      float s = 0.f;
      #pragma unroll
      for (int c = 0; c < 2; c++) {
        float v = acc[r][c][j] + bias_c[c];
        vout[r][c][j] = v;
        s += v * v;
      }
      #pragma unroll
      for (int m = 1; m < 16; m <<= 1) s += __shfl_xor(s, m, 64);
      ss[r][j] = s;
    }
  }
  if (lm == 0) {
    #pragma unroll
    for (int r = 0; r < 2; r++)
      #pragma unroll
      for (int j = 0; j < 4; j++)
        sq[w][r * 16 + lg * 4 + j] = ss[r][j];
  }
  __syncthreads();
  #pragma unroll
  for (int r = 0; r < 2; r++) {
    #pragma unroll
    for (int j = 0; j < 4; j++) {
      int rowl = r * 16 + lg * 4 + j;
      float tot = sq[0][rowl] + sq[1][rowl] + sq[2][rowl] + sq[3][rowl];
      float inv = 1.0f / fmaxf(sqrtf(tot), 1e-12f);
      int row_g = rowblk + rowl;
      unsigned short* rep = (row_g < NQ) ? qrep : drep;
      int rl = (row_g < NQ) ? row_g : row_g - NQ;
      #pragma unroll
      for (int c = 0; c < 2; c++) {
        int col = w * 32 + c * 16 + lm;
        int byteoff = rl * 256 + ((((col >> 3) ^ (rl & 15)) << 4) | ((col & 7) << 1));
        *(unsigned short*)((char*)rep + byteoff) = f2bf(vout[r][c][j] * inv);
      }
    }
  }
}

// ---------------------------------------------------------------------------
// score: block = one query batch (256 q) x 4 doc batches (1024 d).
// Grid 32 x 8 = 256 blocks = 1/CU. 8 waves = 2 (d-dir) x 4 (q-dir);
// wave-tile 64 d x 64 q, mfma_f32_32x32x16_bf16 (A = D rows, B = Q cols).
// Q-tile 64 KB staged once (frags hoisted to regs, then Qt is DEAD and
// overlaid by maxAll/partial); D 128-row chunks double-buffered 2x32 KB.
// Max over doc tokens is over REGISTER indices; per-db result -> maxAll
// (no extra barriers; dbuf barriers order the overlay). One final epilogue
// computes all 4 outputs. LDS total = 128 KB exactly.
__launch_bounds__(512, 2)
__global__ void score_kernel(const unsigned short* __restrict__ qrep,
                             const unsigned short* __restrict__ drep,
                             const float* __restrict__ wmask,
                             float* __restrict__ out) {
  __shared__ __align__(16) char smem[131072];
  char* Qt  = smem;                       // 64 KB, dead after qf hoist
  char* Dt0 = smem + 65536;               // 32 KB
  char* Dt1 = smem + 98304;               // 32 KB
  float* maxAll   = (float*)smem;         // [4 db][2 wr][256 q] = 8 KB (overlay)
  float* partial2 = (float*)(smem + 8192); // [8] (overlay)

  const int t = threadIdx.x;
  const int w = t >> 6, l = t & 63;
  const int col = l & 31, hi = l >> 5;
  const int wr = w >> 2, wc = w & 3;   // 2 (d-dir) x 4 (q-dir)
  const int qb = blockIdx.x;           // 0..31 query batch
  const int dg = blockIdx.y;           // 0..7  doc-batch group

  const char* qsrc = (const char*)qrep + (size_t)qb * 65536;
  const char* dsrc = (const char*)drep + (size_t)dg * 262144;

  // stage Q (64 KB) + D chunk 0 (32 KB)
  #pragma unroll
  for (int i = 0; i < 8; i++)
    gload_lds16(qsrc + i * 8192 + t * 16, Qt + i * 8192 + w * 1024);
  #pragma unroll
  for (int i = 0; i < 4; i++)
    gload_lds16(dsrc + i * 8192 + t * 16, Dt0 + i * 8192 + w * 1024);
  __syncthreads();

  // hoist Q-frags: 2 col-tiles x 8 k-steps (64 VGPR); Qt dead afterwards
  bf16x8 qf[2][8];
  #pragma unroll
  for (int c = 0; c < 2; c++) {
    int n = wc * 64 + c * 32 + col;
    const char* rowb = Qt + n * 256;
    #pragma unroll
    for (int ks = 0; ks < 8; ks++) {
      int ch = (ks * 2 + hi) ^ (n & 15);
      qf[c][ks] = *(const bf16x8*)(rowb + ch * 16);
    }
  }

  f32x16 acc[2][2];
  float vmax[2] = {-INFINITY, -INFINITY};

  for (int db = 0; db < 4; db++) {
    // ---- phase A: stage chunk 2db+1 -> Dt1; compute chunk 2db from Dt0
    {
      const char* nsrc = dsrc + (size_t)(2 * db + 1) * 32768;
      #pragma unroll
      for (int i = 0; i < 4; i++)
        gload_lds16(nsrc + i * 8192 + t * 16, Dt1 + i * 8192 + w * 1024);
    }
    #pragma unroll
    for (int r = 0; r < 2; r++)
      #pragma unroll
      for (int c = 0; c < 2; c++)
        #pragma unroll
        for (int g = 0; g < 16; g++) acc[r][c][g] = 0.f;
    #pragma unroll
    for (int ks = 0; ks < 8; ks++) {
      bf16x8 df[2];
      #pragma unroll
      for (int r = 0; r < 2; r++) {
        int m = wr * 64 + r * 32 + col;
        int ch = (ks * 2 + hi) ^ (m & 15);
        df[r] = *(const bf16x8*)(Dt0 + m * 256 + ch * 16);
      }
      #pragma unroll
      for (int r = 0; r < 2; r++)
        #pragma unroll
        for (int c = 0; c < 2; c++)
          acc[r][c] = __builtin_amdgcn_mfma_f32_32x32x16_bf16(df[r], qf[c][ks], acc[r][c], 0, 0, 0);
    }
    #pragma unroll
    for (int c = 0; c < 2; c++)
      #pragma unroll
      for (int r = 0; r < 2; r++)
        #pragma unroll
        for (int g = 0; g < 16; g++) vmax[c] = fmaxf(vmax[c], acc[r][c][g]);
    __syncthreads();  // chunk 2db+1 landed; all waves done with Dt0

    // ---- phase B: stage chunk 2db+2 -> Dt0 (if any); compute Dt1
    if (db < 3) {
      const char* nsrc = dsrc + (size_t)(2 * db + 2) * 32768;
      #pragma unroll
      for (int i = 0; i < 4; i++)
        gload_lds16(nsrc + i * 8192 + t * 16, Dt0 + i * 8192 + w * 1024);
    }
    #pragma unroll
    for (int r = 0; r < 2; r++)
      #pragma unroll
      for (int c = 0; c < 2; c++)
        #pragma unroll
        for (int g = 0; g < 16; g++) acc[r][c][g] = 0.f;
    #pragma unroll
    for (int ks = 0; ks < 8; ks++) {
      bf16x8 df[2];
      #pragma unroll
      for (int r = 0; r < 2; r++) {
        int m = wr * 64 + r * 32 + col;
        int ch = (ks * 2 + hi) ^ (m & 15);
        df[r] = *(const bf16x8*)(Dt1 + m * 256 + ch * 16);
      }
      #pragma unroll
      for (int r = 0; r < 2; r++)
        #pragma unroll
        for (int c = 0; c < 2; c++)
          acc[r][c] = __builtin_amdgcn_mfma_f32_32x32x16_bf16(df[r], qf[c][ks], acc[r][c], 0, 0, 0);
    }
    #pragma unroll
    for (int c = 0; c < 2; c++)
      #pragma unroll
      for (int r = 0; r < 2; r++)
        #pragma unroll
        for (int g = 0; g < 16; g++) vmax[c] = fmaxf(vmax[c], acc[r][c][g]);

    // ---- per-db store: combine hi-halves, write per-token max (no barrier)
    #pragma unroll
    for (int c = 0; c < 2; c++) {
      float m = vmax[c];
      m = fmaxf(m, __shfl_xor(m, 32, 64));
      if (hi == 0) maxAll[db * 512 + wr * 256 + wc * 64 + c * 32 + col] = m;
      vmax[c] = -INFINITY;
    }
    __syncthreads();  // Dt0 DMA landed; Dt1 free; maxAll[db] visible
  }

  // ---- final epilogue: wave w handles db = w>>1, half h = w&1 (128 tokens)
  {
    int db = w >> 1, h = w & 1;
    int tok0 = h * 128 + l;
    int tok1 = tok0 + 64;
    float m0 = fmaxf(maxAll[db * 512 + tok0], maxAll[db * 512 + 256 + tok0]);
    float m1 = fmaxf(maxAll[db * 512 + tok1], maxAll[db * 512 + 256 + tok1]);
    float contrib = m0 * wmask[qb * 256 + tok0] + m1 * wmask[qb * 256 + tok1];
    #pragma unroll
    for (int off = 1; off < 64; off <<= 1) contrib += __shfl_xor(contrib, off, 64);
    if (l == 0) partial2[w] = contrib;
  }
  __syncthreads();
  if (t < 4)
    out[qb * 32 + dg * 4 + t] = partial2[2 * t] + partial2[2 * t + 1];
}

// ---------------------------------------------------------------------------
extern "C" void kernel_launch(void* const* d_in, const int* in_sizes, int n_in,
                              void* d_out, int out_size, void* d_ws, size_t ws_size,
                              hipStream_t stream) {
  const float* qh  = (const float*)d_in[0];
  const float* dh  = (const float*)d_in[1];
  const float* W   = (const float*)d_in[2];
  const float* b   = (const float*)d_in[3];
  const int* mask  = (const int*)d_in[4];
  float* out = (float*)d_out;

  char* ws = (char*)d_ws;
  unsigned short* qrep = (unsigned short*)(ws);                         // 2 MB
  unsigned short* drep = (unsigned short*)(ws + (1 << 21));             // 2 MB
  unsigned short* WT   = (unsigned short*)(ws + (1 << 22));             // 192 KB
  float* wmaskp        = (float*)(ws + (1 << 22) + (192 << 10));        // 32 KB

  prep_kernel<<<416, 256, 0, stream>>>(W, WT, mask, wmaskp);
  proj_kernel<<<512, 256, 0, stream>>>(qh, dh, WT, b, qrep, drep);
  score_kernel<<<dim3(32, 8), 512, 0, stream>>>(qrep, drep, wmaskp, out);
}